// Round 5
// baseline (168.618 us; speedup 1.0000x reference)
//
#include <hip/hip_runtime.h>
#include <math.h>

#define B 32
#define P1 778
#define NF 1538
#define P2 3000
#define PARAM_DIM 61
#define LATENT 64

#define NCH_O2H 12            // 12*256 = 3072 >= 3000
#define NCH_H2O 8
#define CH_H2O 375            // 8*375 = 3000
#define RED1_BLKS 16
#define POST_BLKS 128

// kmain role block ranges
#define NB_O2H (NCH_O2H * 32)     // 384 (both sets per block)
#define NB_H2O (NCH_H2O * 64)     // 512
#define NB_MAIN (NB_O2H + NB_H2O) // 896

// ws layout (float offsets)
#define PV_OFF  0                           // 2*B*P1 float4 packed verts (x,y,z,|h|^2+64)
#define PV_SZ   (2*B*P1*4)
#define NRM_OFF (PV_OFF + PV_SZ)            // 2*B*P1 float4 normals
#define NRM_SZ  (2*B*P1*4)
#define HP_OFF  (NRM_OFF + NRM_SZ)          // NCH_H2O*2*B*P1 chunk partial min d2
#define HP_SZ   (NCH_H2O*2*B*P1)
#define R1_OFF  (HP_OFF + HP_SZ)            // RED1_BLKS*3
#define RO_OFF  (R1_OFF + RED1_BLKS*3)      // NB_O2H (o-part block partials)
#define RH_OFF  (RO_OFF + NB_O2H)           // POST_BLKS (h-part block partials)

// ---------------- D1: normals + packed verts + small reductions --------------
__global__ __launch_bounds__(256) void kprep(
    const float* __restrict__ recon_x, const float* __restrict__ x,
    const float* __restrict__ mu, const float* __restrict__ logvar,
    const float* __restrict__ recon_xyz, const float* __restrict__ hand_xyz,
    const int* __restrict__ faces, float* __restrict__ ws) {
  __shared__ float smem[5446];
  const int tid = threadIdx.x;
  const int bid = blockIdx.x;
  if (bid < 64) {
    const int set = bid >> 5, b = bid & 31;
    const float* verts = (set == 0 ? recon_xyz : hand_xyz) + b * P1 * 3;
    const int* f = faces + b * NF * 3;
    float4* sv = (float4*)smem;           // 778 float4
    float* sn = smem + P1 * 4;            // 778*3
    float4* pv = (float4*)(ws + PV_OFF) + (size_t)(set * B + b) * P1;
    for (int i = tid; i < P1; i += 256) {
      float vx = verts[3*i], vy = verts[3*i+1], vz = verts[3*i+2];
      sv[i] = make_float4(vx, vy, vz, 0.f);
      pv[i] = make_float4(vx, vy, vz, vx*vx + vy*vy + vz*vz + 64.f);
    }
    for (int i = tid; i < P1 * 3; i += 256) sn[i] = 0.f;
    __syncthreads();
    for (int k = tid; k < NF; k += 256) {
      int i0 = f[3*k], i1 = f[3*k+1], i2 = f[3*k+2];
      float4 v0 = sv[i0], v1 = sv[i1], v2 = sv[i2];
      float e0x = v1.x - v0.x, e0y = v1.y - v0.y, e0z = v1.z - v0.z;
      float e1x = v2.x - v0.x, e1y = v2.y - v0.y, e1z = v2.z - v0.z;
      float fx = e0y * e1z - e0z * e1y;
      float fy = e0z * e1x - e0x * e1z;
      float fz = e0x * e1y - e0y * e1x;
      atomicAdd(&sn[3*i0+0], fx); atomicAdd(&sn[3*i0+1], fy); atomicAdd(&sn[3*i0+2], fz);
      atomicAdd(&sn[3*i1+0], fx); atomicAdd(&sn[3*i1+1], fy); atomicAdd(&sn[3*i1+2], fz);
      atomicAdd(&sn[3*i2+0], fx); atomicAdd(&sn[3*i2+1], fy); atomicAdd(&sn[3*i2+2], fz);
    }
    __syncthreads();
    float4* nout = (float4*)(ws + NRM_OFF) + (size_t)(set * B + b) * P1;
    for (int p = tid; p < P1; p += 256) {
      float nx = sn[3*p], ny = sn[3*p+1], nz = sn[3*p+2];
      float nn = sqrtf(nx*nx + ny*ny + nz*nz);
      float inv = 1.f / fmaxf(nn, 1e-6f);
      nout[p] = make_float4(nx*inv, ny*inv, nz*inv, 0.f);
    }
  } else {
    const int blk = bid - 64;
    const int gtid = blk * 256 + tid, stride = RED1_BLKS * 256;
    float sp = 0.f, sr = 0.f, sk = 0.f;
    for (int i = gtid; i < B * PARAM_DIM; i += stride) { float d = recon_x[i] - x[i]; sp += d * d; }
    for (int i = gtid; i < B * P1 * 3; i += stride)    { float d = recon_xyz[i] - hand_xyz[i]; sr += d * d; }
    for (int i = gtid; i < B * LATENT; i += stride)    { float lv = logvar[i], m = mu[i]; sk += 1.f + lv - m * m - expf(lv); }
    for (int off = 32; off > 0; off >>= 1) {
      sp += __shfl_down(sp, off, 64);
      sr += __shfl_down(sr, off, 64);
      sk += __shfl_down(sk, off, 64);
    }
    const int wv = tid >> 6;
    if ((tid & 63) == 0) { smem[wv*3] = sp; smem[wv*3+1] = sr; smem[wv*3+2] = sk; }
    __syncthreads();
    if (tid == 0) {
      float a = 0.f, bb = 0.f, c = 0.f;
      for (int w = 0; w < 4; ++w) { a += smem[w*3]; bb += smem[w*3+1]; c += smem[w*3+2]; }
      ws[R1_OFF + blk*3+0] = a; ws[R1_OFF + blk*3+1] = bb; ws[R1_OFF + blk*3+2] = c;
    }
  }
}

// ---------------- D2: o2h (both sets + sign + weight) and h2o partial mins ---
__global__ __launch_bounds__(256) void kmain(
    const float* __restrict__ recon_xyz, const float* __restrict__ hand_xyz,
    const float* __restrict__ obj, float* __restrict__ ws) {
  const int tid = threadIdx.x;
  const int bid = blockIdx.x;

  if (bid < NB_O2H) {
    // ---- o2h: per-obj argmin over both sets' hand pts + full loss_o item ----
    __shared__ float4 sA[P1];
    __shared__ float4 sB[P1];
    __shared__ float sred[4];
    const int chunk = bid >> 5, b = bid & 31;
    const float4* pvA = (const float4*)(ws + PV_OFF) + (size_t)b * P1;
    const float4* pvB = pvA + (size_t)B * P1;
    for (int i = tid; i < P1; i += 256) { sA[i] = pvA[i]; sB[i] = pvB[i]; }
    __syncthreads();
    const int q = chunk * 256 + tid;
    const bool act = q < P2;
    float px = 0.f, py = 0.f, pz = 0.f;
    if (act) { const float* op = obj + (size_t)(b * P2 + q) * 3; px = op[0]; py = op[1]; pz = op[2]; }
    const float a0 = -2.f*px, b0 = -2.f*py, c0 = -2.f*pz;
    unsigned bestA = 0xFFFFFFFFu, bestB = 0xFFFFFFFFu;
    #pragma unroll 4
    for (int p = 0; p < P1; p += 2) {
      float4 hA0 = sA[p], hA1 = sA[p+1];
      float4 hB0 = sB[p], hB1 = sB[p+1];
      float dA0 = fmaf(hA0.x, a0, fmaf(hA0.y, b0, fmaf(hA0.z, c0, hA0.w)));
      float dA1 = fmaf(hA1.x, a0, fmaf(hA1.y, b0, fmaf(hA1.z, c0, hA1.w)));
      float dB0 = fmaf(hB0.x, a0, fmaf(hB0.y, b0, fmaf(hB0.z, c0, hB0.w)));
      float dB1 = fmaf(hB1.x, a0, fmaf(hB1.y, b0, fmaf(hB1.z, c0, hB1.w)));
      unsigned kA0 = (__float_as_uint(dA0) & 0xFFFFFC00u) | (unsigned)p;
      unsigned kA1 = (__float_as_uint(dA1) & 0xFFFFFC00u) | (unsigned)(p+1);
      unsigned kB0 = (__float_as_uint(dB0) & 0xFFFFFC00u) | (unsigned)p;
      unsigned kB1 = (__float_as_uint(dB1) & 0xFFFFFC00u) | (unsigned)(p+1);
      unsigned mA = kA0 < kA1 ? kA0 : kA1;
      unsigned mB = kB0 < kB1 ? kB0 : kB1;
      bestA = mA < bestA ? mA : bestA;
      bestB = mB < bestB ? mB : bestB;
    }
    float so_item = 0.f;
    if (act) {
      const float4* nrm = (const float4*)(ws + NRM_OFF);
      int biA = (int)(bestA & 1023u); biA = biA < P1 ? biA : P1 - 1;
      int biB = (int)(bestB & 1023u); biB = biB < P1 ? biB : P1 - 1;
      float4 hA = sA[biA], hB = sB[biB];
      float4 nA = nrm[(size_t)b * P1 + biA];
      float4 nB = nrm[(size_t)(B + b) * P1 + biB];
      float dxA = px - hA.x, dyA = py - hA.y, dzA = pz - hA.z;
      float d2A = fmaf(dxA, dxA, fmaf(dyA, dyA, dzA * dzA));
      float dtA = nA.x * dxA + nA.y * dyA + nA.z * dzA;
      float sgA = (dtA > 0.f) ? 1.f : ((dtA < 0.f) ? -1.f : 0.f);
      float osA = sqrtf(d2A) * sgA;
      float dxB = px - hB.x, dyB = py - hB.y, dzB = pz - hB.z;
      float d2B = fmaf(dxB, dxB, fmaf(dyB, dyB, dzB * dzB));
      float dtB = nB.x * dxB + nB.y * dyB + nB.z * dzB;
      float sgB = (dtB > 0.f) ? 1.f : ((dtB < 0.f) ? -1.f : 0.f);
      float osB = sqrtf(d2B) * sgB;
      bool wdist = (osB < 0.01f) && (osB > -0.005f);
      float w = (osA < 0.f) ? 1.5f : (wdist ? 1.f : 0.1f);
      so_item = fabsf(osA - osB) * w;
    }
    for (int off = 32; off > 0; off >>= 1) so_item += __shfl_down(so_item, off, 64);
    if ((tid & 63) == 0) sred[tid >> 6] = so_item;
    __syncthreads();
    if (tid == 0) ws[RO_OFF + bid] = sred[0] + sred[1] + sred[2] + sred[3];

  } else {
    // ---- h2o: per-hand partial min over one obj chunk ----
    __shared__ float4 s4[CH_H2O];
    const int t = bid - NB_O2H;
    const int chunk = t >> 6, r = t & 63, set = r >> 5, b = r & 31;
    const float* verts = (set == 0 ? recon_xyz : hand_xyz) + b * P1 * 3;
    const float* op = obj + (size_t)(b * P2 + chunk * CH_H2O) * 3;
    for (int i = tid; i < CH_H2O; i += 256) {
      float ox = op[3*i], oy = op[3*i+1], oz = op[3*i+2];
      s4[i] = make_float4(ox, oy, oz, ox*ox + oy*oy + oz*oz);
    }
    __syncthreads();
    float* part = ws + HP_OFF + (size_t)((chunk * 2 + set) * B + b) * P1;
    const int p0 = tid, p1 = tid + 256, p2 = tid + 512;
    float ax = verts[3*p0], ay = verts[3*p0+1], az = verts[3*p0+2];
    float bx = verts[3*p1], by = verts[3*p1+1], bz = verts[3*p1+2];
    float cx = verts[3*p2], cy = verts[3*p2+1], cz = verts[3*p2+2];
    float h2a = ax*ax+ay*ay+az*az, h2b = bx*bx+by*by+bz*bz, h2c = cx*cx+cy*cy+cz*cz;
    float nax = -2.f*ax, nay = -2.f*ay, naz = -2.f*az;
    float nbx = -2.f*bx, nby = -2.f*by, nbz = -2.f*bz;
    float ncx = -2.f*cx, ncy = -2.f*cy, ncz = -2.f*cz;
    float m0 = 3.0e38f, m1 = 3.0e38f, m2 = 3.0e38f;
    #pragma unroll 4
    for (int qq = 0; qq < CH_H2O; ++qq) {
      float4 o = s4[qq];
      m0 = fminf(m0, fmaf(o.x, nax, fmaf(o.y, nay, fmaf(o.z, naz, o.w))));
      m1 = fminf(m1, fmaf(o.x, nbx, fmaf(o.y, nby, fmaf(o.z, nbz, o.w))));
      m2 = fminf(m2, fmaf(o.x, ncx, fmaf(o.y, ncy, fmaf(o.z, ncz, o.w))));
    }
    part[p0] = m0 + h2a;
    part[p1] = m1 + h2b;
    part[p2] = m2 + h2c;
    if (tid < P1 - 768) {
      const int p3 = 768 + tid;
      float tx = verts[3*p3], ty = verts[3*p3+1], tz = verts[3*p3+2];
      float h2t = tx*tx+ty*ty+tz*tz;
      float ntx = -2.f*tx, nty = -2.f*ty, ntz = -2.f*tz;
      float m3 = 3.0e38f;
      for (int qq = 0; qq < CH_H2O; ++qq) {
        float4 o = s4[qq];
        m3 = fminf(m3, fmaf(o.x, ntx, fmaf(o.y, nty, fmaf(o.z, ntz, o.w))));
      }
      part[p3] = m3 + h2t;
    }
  }
}

// ---------------- D3: h-part (fold chunk mins, weight by vw^0.4) -------------
__global__ __launch_bounds__(256) void kpost(const float* __restrict__ vw,
                                             float* __restrict__ ws) {
  __shared__ float sred[4];
  const int gtid = blockIdx.x * 256 + threadIdx.x;
  const int stride = POST_BLKS * 256;
  float sh = 0.f;
  for (int i = gtid; i < B * P1; i += stride) {
    const int p = i % P1;
    float m0 = 3.0e38f, m1 = 3.0e38f;
    #pragma unroll
    for (int c = 0; c < NCH_H2O; ++c) {
      m0 = fminf(m0, ws[HP_OFF + (size_t)(c*2+0) * B * P1 + i]);
      m1 = fminf(m1, ws[HP_OFF + (size_t)(c*2+1) * B * P1 + i]);
    }
    m0 = fmaxf(m0, 0.f); m1 = fmaxf(m1, 0.f);
    sh += fabsf(sqrtf(m0) - sqrtf(m1)) * powf(vw[p], 0.4f);
  }
  for (int off = 32; off > 0; off >>= 1) sh += __shfl_down(sh, off, 64);
  if ((threadIdx.x & 63) == 0) sred[threadIdx.x >> 6] = sh;
  __syncthreads();
  if (threadIdx.x == 0)
    ws[RH_OFF + blockIdx.x] = sred[0] + sred[1] + sred[2] + sred[3];
}

// ---------------- D4: finalize (single wave) ---------------------------------
__global__ void kfin(const float* __restrict__ ws, float* __restrict__ out) {
  const int lane = threadIdx.x;
  float sp = 0.f, sr = 0.f, sk = 0.f, sh = 0.f, so = 0.f;
  for (int i = lane; i < RED1_BLKS; i += 64) {
    sp += ws[R1_OFF + i*3+0]; sr += ws[R1_OFF + i*3+1]; sk += ws[R1_OFF + i*3+2];
  }
  for (int i = lane; i < NB_O2H; i += 64) so += ws[RO_OFF + i];
  for (int i = lane; i < POST_BLKS; i += 64) sh += ws[RH_OFF + i];
  for (int off = 32; off > 0; off >>= 1) {
    sp += __shfl_down(sp, off, 64);
    sr += __shfl_down(sr, off, 64);
    sk += __shfl_down(sk, off, 64);
    sh += __shfl_down(sh, off, 64);
    so += __shfl_down(so, off, 64);
  }
  if (lane == 0) {
    float param_loss = sp / (float)B;
    float recon_loss = sr / (float)B;
    float KLD = -0.5f * sk / (float)B;
    float cvae = recon_loss + KLD;
    float loss_h = 35.f * (1.f - 0.005f) * sh / (float)(B * P1);
    float loss_o = 30.f * (1.f - 0.005f) * so / (float)(B * P2);
    float ho = loss_h + loss_o;
    out[0] = cvae + 0.1f * param_loss + 10.f * ho;
    out[1] = param_loss;
    out[2] = ho;
    out[3] = recon_loss;
    out[4] = KLD;
  }
}

extern "C" void kernel_launch(void* const* d_in, const int* in_sizes, int n_in,
                              void* d_out, int out_size, void* d_ws, size_t ws_size,
                              hipStream_t stream) {
  const float* recon_x   = (const float*)d_in[0];
  const float* x         = (const float*)d_in[1];
  const float* mu        = (const float*)d_in[2];
  const float* logvar    = (const float*)d_in[3];
  const float* recon_xyz = (const float*)d_in[4];
  const float* hand_xyz  = (const float*)d_in[5];
  const int*   faces     = (const int*)d_in[6];
  const float* obj       = (const float*)d_in[7];
  const float* vw        = (const float*)d_in[8];
  float* ws = (float*)d_ws;
  float* out = (float*)d_out;

  kprep<<<dim3(64 + RED1_BLKS), 256, 0, stream>>>(recon_x, x, mu, logvar,
                                                  recon_xyz, hand_xyz, faces, ws);
  kmain<<<dim3(NB_MAIN), 256, 0, stream>>>(recon_xyz, hand_xyz, obj, ws);
  kpost<<<dim3(POST_BLKS), 256, 0, stream>>>(vw, ws);
  kfin<<<1, 64, 0, stream>>>(ws, out);
}

// Round 6
// 143.664 us; speedup vs baseline: 1.1737x; 1.1737x over previous
//
#include <hip/hip_runtime.h>
#include <math.h>

#define B 32
#define P1 778
#define NF 1538
#define P2 3000
#define PARAM_DIM 61
#define LATENT 64

#define NCH_O2H 12            // 12*256 = 3072 >= 3000
#define NCH_H2O 15
#define CH_H2O 200            // 15*200 = 3000
#define RED1_BLKS 16
#define POST_BLKS 192

// kmain role block ranges (o2h first: longest blocks start earliest)
#define NB_O2H (NCH_O2H * 64)     // 768
#define NB_H2O (NCH_H2O * 64)     // 960
#define NB_MAIN (NB_O2H + NB_H2O) // 1728

// ws layout (float offsets)
#define NRM_OFF 0                           // 2*B*P1 float4 normals
#define NRM_SZ  (2*B*P1*4)
#define OS_OFF  (NRM_OFF + NRM_SZ)          // 2*B*P2 signed o2h dists
#define OS_SZ   (2*B*P2)
#define HP_OFF  (OS_OFF + OS_SZ)            // NCH_H2O*2*B*P1 chunk partial min d2
#define HP_SZ   (NCH_H2O*2*B*P1)
#define R1_OFF  (HP_OFF + HP_SZ)            // RED1_BLKS*3
#define RP_OFF  (R1_OFF + RED1_BLKS*3)      // POST_BLKS*2 (sh, so)

// ---------------- D1: normals + small reductions -----------------------------
__global__ __launch_bounds__(256) void kprep(
    const float* __restrict__ recon_x, const float* __restrict__ x,
    const float* __restrict__ mu, const float* __restrict__ logvar,
    const float* __restrict__ recon_xyz, const float* __restrict__ hand_xyz,
    const int* __restrict__ faces, float* __restrict__ ws) {
  __shared__ float smem[5446];
  const int tid = threadIdx.x;
  const int bid = blockIdx.x;
  if (bid < 64) {
    const int set = bid >> 5, b = bid & 31;
    const float* verts = (set == 0 ? recon_xyz : hand_xyz) + b * P1 * 3;
    const int* f = faces + b * NF * 3;
    float4* sv = (float4*)smem;           // 778 float4
    float* sn = smem + P1 * 4;            // 778*3
    for (int i = tid; i < P1; i += 256)
      sv[i] = make_float4(verts[3*i], verts[3*i+1], verts[3*i+2], 0.f);
    for (int i = tid; i < P1 * 3; i += 256) sn[i] = 0.f;
    __syncthreads();
    for (int k = tid; k < NF; k += 256) {
      int i0 = f[3*k], i1 = f[3*k+1], i2 = f[3*k+2];
      float4 v0 = sv[i0], v1 = sv[i1], v2 = sv[i2];
      float e0x = v1.x - v0.x, e0y = v1.y - v0.y, e0z = v1.z - v0.z;
      float e1x = v2.x - v0.x, e1y = v2.y - v0.y, e1z = v2.z - v0.z;
      float fx = e0y * e1z - e0z * e1y;
      float fy = e0z * e1x - e0x * e1z;
      float fz = e0x * e1y - e0y * e1x;
      atomicAdd(&sn[3*i0+0], fx); atomicAdd(&sn[3*i0+1], fy); atomicAdd(&sn[3*i0+2], fz);
      atomicAdd(&sn[3*i1+0], fx); atomicAdd(&sn[3*i1+1], fy); atomicAdd(&sn[3*i1+2], fz);
      atomicAdd(&sn[3*i2+0], fx); atomicAdd(&sn[3*i2+1], fy); atomicAdd(&sn[3*i2+2], fz);
    }
    __syncthreads();
    float4* nout = (float4*)(ws + NRM_OFF) + (size_t)(set * B + b) * P1;
    for (int p = tid; p < P1; p += 256) {
      float nx = sn[3*p], ny = sn[3*p+1], nz = sn[3*p+2];
      float nn = sqrtf(nx*nx + ny*ny + nz*nz);
      float inv = 1.f / fmaxf(nn, 1e-6f);
      nout[p] = make_float4(nx*inv, ny*inv, nz*inv, 0.f);
    }
  } else {
    const int blk = bid - 64;
    const int gtid = blk * 256 + tid, stride = RED1_BLKS * 256;
    float sp = 0.f, sr = 0.f, sk = 0.f;
    for (int i = gtid; i < B * PARAM_DIM; i += stride) { float d = recon_x[i] - x[i]; sp += d * d; }
    for (int i = gtid; i < B * P1 * 3; i += stride)    { float d = recon_xyz[i] - hand_xyz[i]; sr += d * d; }
    for (int i = gtid; i < B * LATENT; i += stride)    { float lv = logvar[i], m = mu[i]; sk += 1.f + lv - m * m - expf(lv); }
    for (int off = 32; off > 0; off >>= 1) {
      sp += __shfl_down(sp, off, 64);
      sr += __shfl_down(sr, off, 64);
      sk += __shfl_down(sk, off, 64);
    }
    const int wv = tid >> 6;
    if ((tid & 63) == 0) { smem[wv*3] = sp; smem[wv*3+1] = sr; smem[wv*3+2] = sk; }
    __syncthreads();
    if (tid == 0) {
      float a = 0.f, bb = 0.f, c = 0.f;
      for (int w = 0; w < 4; ++w) { a += smem[w*3]; bb += smem[w*3+1]; c += smem[w*3+2]; }
      ws[R1_OFF + blk*3+0] = a; ws[R1_OFF + blk*3+1] = bb; ws[R1_OFF + blk*3+2] = c;
    }
  }
}

// ---------------- D2: o2h signed dists (per set) and h2o partial mins --------
__global__ __launch_bounds__(256) void kmain(
    const float* __restrict__ recon_xyz, const float* __restrict__ hand_xyz,
    const float* __restrict__ obj, float* __restrict__ ws) {
  __shared__ float4 s4[P1];          // o2h: 778 packed hand pts; h2o: first 200 = obj pts
  const int tid = threadIdx.x;
  const int bid = blockIdx.x;

  if (bid < NB_O2H) {
    // ---- o2h: one (set,b,chunk); argmin over full hand set; signed dist out --
    const int chunk = bid >> 6, r = bid & 63, set = r >> 5, b = r & 31;
    const float* verts = (set == 0 ? recon_xyz : hand_xyz) + b * P1 * 3;
    for (int i = tid; i < P1; i += 256) {
      float vx = verts[3*i], vy = verts[3*i+1], vz = verts[3*i+2];
      s4[i] = make_float4(vx, vy, vz, vx*vx + vy*vy + vz*vz + 64.f);  // d' > 0
    }
    __syncthreads();
    const int q = chunk * 256 + tid;
    const bool act = q < P2;
    float px = 0.f, py = 0.f, pz = 0.f;
    if (act) { const float* op = obj + (size_t)(b * P2 + q) * 3; px = op[0]; py = op[1]; pz = op[2]; }
    const float a0 = -2.f*px, b0 = -2.f*py, c0 = -2.f*pz;
    unsigned best = 0xFFFFFFFFu;
    #pragma unroll 4
    for (int p = 0; p < P1; p += 2) {
      float4 h0 = s4[p], h1 = s4[p+1];
      float d0 = fmaf(h0.x, a0, fmaf(h0.y, b0, fmaf(h0.z, c0, h0.w)));
      float d1 = fmaf(h1.x, a0, fmaf(h1.y, b0, fmaf(h1.z, c0, h1.w)));
      unsigned k0 = (__float_as_uint(d0) & 0xFFFFFC00u) | (unsigned)p;
      unsigned k1 = (__float_as_uint(d1) & 0xFFFFFC00u) | (unsigned)(p+1);
      unsigned m = k0 < k1 ? k0 : k1;
      best = m < best ? m : best;
    }
    if (act) {
      int bi = (int)(best & 1023u); bi = bi < P1 ? bi : P1 - 1;
      float4 h = s4[bi];
      float4 n = ((const float4*)(ws + NRM_OFF))[(size_t)(set * B + b) * P1 + bi];
      float dx = px - h.x, dy = py - h.y, dz = pz - h.z;
      float d2 = fmaf(dx, dx, fmaf(dy, dy, dz * dz));
      float dt = n.x * dx + n.y * dy + n.z * dz;
      float sg = (dt > 0.f) ? 1.f : ((dt < 0.f) ? -1.f : 0.f);
      ws[OS_OFF + (size_t)(set * B + b) * P2 + q] = sqrtf(d2) * sg;
    }

  } else {
    // ---- h2o: per-hand partial min over one 200-pt obj chunk ----
    const int t = bid - NB_O2H;
    const int chunk = t >> 6, r = t & 63, set = r >> 5, b = r & 31;
    const float* verts = (set == 0 ? recon_xyz : hand_xyz) + b * P1 * 3;
    const float* op = obj + (size_t)(b * P2 + chunk * CH_H2O) * 3;
    for (int i = tid; i < CH_H2O; i += 256) {
      float ox = op[3*i], oy = op[3*i+1], oz = op[3*i+2];
      s4[i] = make_float4(ox, oy, oz, ox*ox + oy*oy + oz*oz);
    }
    __syncthreads();
    float* part = ws + HP_OFF + (size_t)((chunk * 2 + set) * B + b) * P1;
    const int p0 = tid, p1 = tid + 256, p2 = tid + 512;
    float ax = verts[3*p0], ay = verts[3*p0+1], az = verts[3*p0+2];
    float bx = verts[3*p1], by = verts[3*p1+1], bz = verts[3*p1+2];
    float cx = verts[3*p2], cy = verts[3*p2+1], cz = verts[3*p2+2];
    float h2a = ax*ax+ay*ay+az*az, h2b = bx*bx+by*by+bz*bz, h2c = cx*cx+cy*cy+cz*cz;
    float nax = -2.f*ax, nay = -2.f*ay, naz = -2.f*az;
    float nbx = -2.f*bx, nby = -2.f*by, nbz = -2.f*bz;
    float ncx = -2.f*cx, ncy = -2.f*cy, ncz = -2.f*cz;
    float m0 = 3.0e38f, m1 = 3.0e38f, m2 = 3.0e38f;
    #pragma unroll 4
    for (int qq = 0; qq < CH_H2O; ++qq) {
      float4 o = s4[qq];
      m0 = fminf(m0, fmaf(o.x, nax, fmaf(o.y, nay, fmaf(o.z, naz, o.w))));
      m1 = fminf(m1, fmaf(o.x, nbx, fmaf(o.y, nby, fmaf(o.z, nbz, o.w))));
      m2 = fminf(m2, fmaf(o.x, ncx, fmaf(o.y, ncy, fmaf(o.z, ncz, o.w))));
    }
    part[p0] = m0 + h2a;
    part[p1] = m1 + h2b;
    part[p2] = m2 + h2c;
    if (tid < P1 - 768) {
      const int p3 = 768 + tid;
      float tx = verts[3*p3], ty = verts[3*p3+1], tz = verts[3*p3+2];
      float h2t = tx*tx+ty*ty+tz*tz;
      float ntx = -2.f*tx, nty = -2.f*ty, ntz = -2.f*tz;
      float m3 = 3.0e38f;
      for (int qq = 0; qq < CH_H2O; ++qq) {
        float4 o = s4[qq];
        m3 = fminf(m3, fmaf(o.x, ntx, fmaf(o.y, nty, fmaf(o.z, ntz, o.w))));
      }
      part[p3] = m3 + h2t;
    }
  }
}

// ---------------- D3: combine o-part + h-part, block partials ----------------
__global__ __launch_bounds__(256) void kpost(const float* __restrict__ vw,
                                             float* __restrict__ ws) {
  __shared__ float sred[8];
  const int gtid = blockIdx.x * 256 + threadIdx.x;
  const int stride = POST_BLKS * 256;
  float so = 0.f, sh = 0.f;
  // o-part: coalesced pairwise combine of the two signed-distance arrays
  for (int i = gtid; i < B * P2; i += stride) {
    float osA = ws[OS_OFF + i];
    float osB = ws[OS_OFF + (size_t)B * P2 + i];
    bool wdist = (osB < 0.01f) && (osB > -0.005f);
    float w = (osA < 0.f) ? 1.5f : (wdist ? 1.f : 0.1f);
    so += fabsf(osA - osB) * w;
  }
  // h-part: fold 15 chunk partial mins per set, weight by vw^0.4
  for (int i = gtid; i < B * P1; i += stride) {
    const int p = i % P1;
    float m0 = 3.0e38f, m1 = 3.0e38f;
    #pragma unroll
    for (int c = 0; c < NCH_H2O; ++c) {
      m0 = fminf(m0, ws[HP_OFF + (size_t)(c*2+0) * B * P1 + i]);
      m1 = fminf(m1, ws[HP_OFF + (size_t)(c*2+1) * B * P1 + i]);
    }
    m0 = fmaxf(m0, 0.f); m1 = fmaxf(m1, 0.f);
    sh += fabsf(sqrtf(m0) - sqrtf(m1)) * powf(vw[p], 0.4f);
  }
  for (int off = 32; off > 0; off >>= 1) {
    sh += __shfl_down(sh, off, 64);
    so += __shfl_down(so, off, 64);
  }
  const int wv = threadIdx.x >> 6;
  if ((threadIdx.x & 63) == 0) { sred[wv*2] = sh; sred[wv*2+1] = so; }
  __syncthreads();
  if (threadIdx.x == 0) {
    float a = 0.f, b = 0.f;
    for (int w = 0; w < 4; ++w) { a += sred[w*2]; b += sred[w*2+1]; }
    ws[RP_OFF + blockIdx.x*2+0] = a;
    ws[RP_OFF + blockIdx.x*2+1] = b;
  }
}

// ---------------- D4: finalize (single wave) ---------------------------------
__global__ void kfin(const float* __restrict__ ws, float* __restrict__ out) {
  const int lane = threadIdx.x;
  float sp = 0.f, sr = 0.f, sk = 0.f, sh = 0.f, so = 0.f;
  for (int i = lane; i < RED1_BLKS; i += 64) {
    sp += ws[R1_OFF + i*3+0]; sr += ws[R1_OFF + i*3+1]; sk += ws[R1_OFF + i*3+2];
  }
  for (int i = lane; i < POST_BLKS; i += 64) {
    sh += ws[RP_OFF + i*2+0]; so += ws[RP_OFF + i*2+1];
  }
  for (int off = 32; off > 0; off >>= 1) {
    sp += __shfl_down(sp, off, 64);
    sr += __shfl_down(sr, off, 64);
    sk += __shfl_down(sk, off, 64);
    sh += __shfl_down(sh, off, 64);
    so += __shfl_down(so, off, 64);
  }
  if (lane == 0) {
    float param_loss = sp / (float)B;
    float recon_loss = sr / (float)B;
    float KLD = -0.5f * sk / (float)B;
    float cvae = recon_loss + KLD;
    float loss_h = 35.f * (1.f - 0.005f) * sh / (float)(B * P1);
    float loss_o = 30.f * (1.f - 0.005f) * so / (float)(B * P2);
    float ho = loss_h + loss_o;
    out[0] = cvae + 0.1f * param_loss + 10.f * ho;
    out[1] = param_loss;
    out[2] = ho;
    out[3] = recon_loss;
    out[4] = KLD;
  }
}

extern "C" void kernel_launch(void* const* d_in, const int* in_sizes, int n_in,
                              void* d_out, int out_size, void* d_ws, size_t ws_size,
                              hipStream_t stream) {
  const float* recon_x   = (const float*)d_in[0];
  const float* x         = (const float*)d_in[1];
  const float* mu        = (const float*)d_in[2];
  const float* logvar    = (const float*)d_in[3];
  const float* recon_xyz = (const float*)d_in[4];
  const float* hand_xyz  = (const float*)d_in[5];
  const int*   faces     = (const int*)d_in[6];
  const float* obj       = (const float*)d_in[7];
  const float* vw        = (const float*)d_in[8];
  float* ws = (float*)d_ws;
  float* out = (float*)d_out;

  kprep<<<dim3(64 + RED1_BLKS), 256, 0, stream>>>(recon_x, x, mu, logvar,
                                                  recon_xyz, hand_xyz, faces, ws);
  kmain<<<dim3(NB_MAIN), 256, 0, stream>>>(recon_xyz, hand_xyz, obj, ws);
  kpost<<<dim3(POST_BLKS), 256, 0, stream>>>(vw, ws);
  kfin<<<1, 64, 0, stream>>>(ws, out);
}